// Round 7
// baseline (230.925 us; speedup 1.0000x reference)
//
#include <hip/hip_runtime.h>
#include <hip/hip_bf16.h>

#define N_NODES 20000
#define N_EDGES 640000
#define NRELS 20
#define MAXDEG 96
#define CHUNKS 53                      // ceil(20000 / 384)
#define GEMM_BLOCKS (NRELS * CHUNKS)   // 1060
#define FILL_BLOCKS 2500               // 640000 / 256

typedef __attribute__((ext_vector_type(8))) short short8;
typedef __attribute__((ext_vector_type(8))) unsigned short ushort8;
typedef __attribute__((ext_vector_type(4))) float floatx4;
typedef unsigned short u16;
typedef unsigned int u32;

__device__ __forceinline__ float bf2f(u16 u){
  union { u32 i; float f; } v; v.i = ((u32)u) << 16; return v.f;
}
__device__ __forceinline__ u16 f2bf(float f){
  __hip_bfloat16 b = __float2bfloat16(f);
  return __builtin_bit_cast(u16, b);
}

// ---------------- K0: fused {cast h->bf16 + count + rank} | {wfrag} ----------
// wfrag layout: [rel][frag = ks*8+nf][lane][8 bf16]  (MFMA fragment order)
//   element (r, row o, k i) -> ks=i>>5, sub=(i>>3)&3, j=i&7, nf=o>>4,
//   lane l = (sub<<4)|(o&15); reference reshape semantics for the value.
__global__ __launch_bounds__(256) void k_prep(
    const float* __restrict__ h, u16* __restrict__ hb,
    const int* __restrict__ dst, int* __restrict__ counts, int* __restrict__ rank,
    const float* __restrict__ weight, const float* __restrict__ w_comp,
    u16* __restrict__ wfrag){
  const int b = blockIdx.x;
  if (b < 2500){
    int tidg = b * 256 + threadIdx.x;
    int i = tidg * 4;
    float4 v = *(const float4*)(h + i);
    u16 o[4] = { f2bf(v.x), f2bf(v.y), f2bf(v.z), f2bf(v.w) };
    *(ushort4*)(hb + i) = *(ushort4*)o;
    rank[tidg] = atomicAdd(&counts[dst[tidg]], 1);
  } else {
    int f = (b - 2500) * 256 + threadIdx.x;      // < 20*128*128 exactly
    int i  = f & 127;
    int o  = (f >> 7) & 127;
    int r  = f >> 14;
    int q  = r * 128 + i;                        // reference reshape semantics
    int rr = q % 20, ii = q / 20;
    float acc = 0.f;
    #pragma unroll
    for (int bb = 0; bb < 8; ++bb)
      acc += w_comp[rr * 8 + bb] * weight[ii * 1024 + bb * 128 + o];
    int ks = i >> 5, sub = (i >> 3) & 3, j = i & 7, nf = o >> 4;
    int l  = (sub << 4) | (o & 15);
    wfrag[((r * 32 + ks * 8 + nf) * 64 + l) * 8 + j] = f2bf(acc);
  }
}

// ---------------- K1: B-resident GEMM (1 rel/block, 3 m-tiles) + CSR fill ----
// xW rows stored PERMUTED: position p = (c&15)*8 + (c>>4)  (lane-major pack)
__global__ __launch_bounds__(256, 3) void k_gemm_fill(
    const u16* __restrict__ hb, const u16* __restrict__ wfrag, u16* __restrict__ xW,
    const int* __restrict__ dst, const int* __restrict__ srcv,
    const int* __restrict__ ety, const int* __restrict__ rank,
    int* __restrict__ gidx){
  if (blockIdx.x >= GEMM_BLOCKS){                // ---- fill role ----
    int e = (blockIdx.x - GEMM_BLOCKS) * 256 + threadIdx.x;
    if (e < N_EDGES)
      gidx[dst[e] * MAXDEG + rank[e]] = ety[e] * N_NODES + srcv[e];
    return;
  }
  // ---- gemm role ----
  __shared__ u16 Bs[16384];                      // 32 KB, fragment-major
  const int rel   = blockIdx.x / CHUNKS;
  const int chunk = blockIdx.x % CHUNKS;
  const int tid   = threadIdx.x;
  {                                              // linear 32KB stage, coalesced
    const u16* wb = wfrag + rel * 16384;
    #pragma unroll
    for (int jj = 0; jj < 8; ++jj){
      int idx = tid + jj * 256;
      *(int4*)((char*)Bs + idx * 16) = *(const int4*)(wb + idx * 8);
    }
  }
  __syncthreads();                               // the ONLY barrier
  const int wave = tid >> 6, lane = tid & 63;
  const int arow = lane & 15;
  const int ak   = (lane >> 4) * 8;
  const char* lbase = (const char*)Bs + lane * 16;
  const short8 az = __builtin_bit_cast(short8, make_int4(0, 0, 0, 0));
  for (int tt = 0; tt < 3; ++tt){
    const int mb = chunk * 384 + tt * 128;
    if (mb >= N_NODES) break;
    const int m0w = mb + wave * 32;
    short8 a[2][4];
    #pragma unroll
    for (int mf = 0; mf < 2; ++mf){
      int row = m0w + mf * 16 + arow;
      bool ok = row < N_NODES;
      #pragma unroll
      for (int ks = 0; ks < 4; ++ks)
        a[mf][ks] = ok ? *(const short8*)(hb + (size_t)row * 128 + ks * 32 + ak) : az;
    }
    floatx4 acc[2][8] = {};
    #pragma unroll
    for (int ks = 0; ks < 4; ++ks){
      #pragma unroll
      for (int nf = 0; nf < 8; ++nf){
        short8 bfr = *(const short8*)(lbase + ((ks * 8 + nf) << 10)); // static offs
        acc[0][nf] = __builtin_amdgcn_mfma_f32_16x16x32_bf16(a[0][ks], bfr, acc[0][nf], 0, 0, 0);
        acc[1][nf] = __builtin_amdgcn_mfma_f32_16x16x32_bf16(a[1][ks], bfr, acc[1][nf], 0, 0, 0);
      }
    }
    const size_t rbase = (size_t)rel * N_NODES;
    #pragma unroll
    for (int mf = 0; mf < 2; ++mf)
    #pragma unroll
    for (int j = 0; j < 4; ++j){
      int row = m0w + mf * 16 + ((lane >> 4) << 2) + j;   // C/D row=(l>>4)*4+j
      if (row < N_NODES){
        ushort8 u;
        #pragma unroll
        for (int nf = 0; nf < 8; ++nf) u[nf] = f2bf(acc[mf][nf][j]);
        *(ushort8*)(xW + (rbase + row) * 128 + (lane & 15) * 8) = u;  // 16B store
      }
    }
  }
}

// ---------------- K2: gather + segment-sum + relu (16-deep MLP) --------------
__global__ __launch_bounds__(256) void k_agg(const int* __restrict__ counts,
    const int* __restrict__ gidx, const u16* __restrict__ xW, float* __restrict__ out){
  const int n = blockIdx.x * 4 + (threadIdx.x >> 6);
  const int t = threadIdx.x & 63;                // owns perm positions 2t, 2t+1
  const int len = counts[n];
  const int* gb = gidx + n * MAXDEG;
  float2 a[16];
  #pragma unroll
  for (int j = 0; j < 16; ++j) a[j] = make_float2(0.f, 0.f);
  int e = 0;
  for (; e + 16 <= len; e += 16){
    int g[16];
    #pragma unroll
    for (int j = 0; j < 16; ++j) g[j] = gb[e + j];
    #pragma unroll
    for (int j = 0; j < 16; ++j){
      u32 pk = *(const u32*)(xW + (size_t)g[j] * 128 + t * 2);
      a[j].x += bf2f((u16)(pk & 0xffffu));
      a[j].y += bf2f((u16)(pk >> 16));
    }
  }
  for (; e < len; ++e){
    int g = gb[e];
    u32 pk = *(const u32*)(xW + (size_t)g * 128 + t * 2);
    a[0].x += bf2f((u16)(pk & 0xffffu));
    a[0].y += bf2f((u16)(pk >> 16));
  }
  float2 s = make_float2(0.f, 0.f);
  #pragma unroll
  for (int j = 0; j < 16; ++j){ s.x += a[j].x; s.y += a[j].y; }
  // perm position p -> channel c = (p&7)*16 + (p>>3); p0=2t, p1=2t+1 -> c0, c0+16
  const int c0 = ((2 * t) & 7) * 16 + (t >> 2);
  out[(size_t)n * 128 + c0]      = fmaxf(s.x, 0.f);
  out[(size_t)n * 128 + c0 + 16] = fmaxf(s.y, 0.f);
}

// ---------------- launcher ---------------------------------------------------
extern "C" void kernel_launch(void* const* d_in, const int* in_sizes, int n_in,
                              void* d_out, int out_size, void* d_ws, size_t ws_size,
                              hipStream_t stream){
  const float* h      = (const float*)d_in[0];
  const float* weight = (const float*)d_in[1];
  const float* w_comp = (const float*)d_in[2];
  const int* src      = (const int*)d_in[3];
  const int* dst      = (const int*)d_in[4];
  const int* etype    = (const int*)d_in[5];
  float* out = (float*)d_out;

  char* p = (char*)d_ws;
  u16* xW      = (u16*)p;  p += 102400000;       // [20][20000][128] bf16 (perm rows)
  u16* hb      = (u16*)p;  p += 5120000;
  u16* wfrag   = (u16*)p;  p += 655360;          // fragment-major weights
  int* counts  = (int*)p;  p += 80000;
  int* rank    = (int*)p;  p += 2560000;
  int* gidx    = (int*)p;  /* 20000*96*4 = 7,680,000 B */   // total ~118.5 MB

  hipMemsetAsync(counts, 0, N_NODES * sizeof(int), stream);
  k_prep<<<dim3(3780), dim3(256), 0, stream>>>(h, hb, dst, counts, rank,
                                               weight, w_comp, wfrag);
  k_gemm_fill<<<dim3(GEMM_BLOCKS + FILL_BLOCKS), dim3(256), 0, stream>>>(
      hb, wfrag, xW, dst, src, etype, rank, gidx);
  k_agg<<<dim3(N_NODES / 4), dim3(256), 0, stream>>>(counts, gidx, xW, out);
}